// Round 12
// baseline (290.082 us; speedup 1.0000x reference)
//
#include <hip/hip_runtime.h>
#include <math.h>

#define H  64
#define F  32
#define NB 4      // batch columns per block
#define NT 1024   // 16 waves: 0-7 L0 (8 units each, gate-pair cols), 8-15 L1
#define HS 80     // h row stride (shorts): 160B -> 2-way banks max (free)

typedef __attribute__((ext_vector_type(8))) short   s8v;   // 8 bf16 payload
typedef __attribute__((ext_vector_type(8))) __bf16  bf8v;  // MFMA operand type
typedef __attribute__((ext_vector_type(4))) float   f4v;   // MFMA accumulator

__device__ __forceinline__ unsigned short f2bf(float x) {   // weight init only
    unsigned u = __builtin_bit_cast(unsigned, x);
    u += 0x7FFFu + ((u >> 16) & 1u);          // RNE
    return (unsigned short)(u >> 16);
}
// HW packed f32->bf16 RNE convert (1 instr)
__device__ __forceinline__ unsigned cvtpk(float a, float b) {
    unsigned r;
    asm("v_cvt_pk_bf16_f32 %0, %1, %2" : "=v"(r) : "v"(a), "v"(b));
    return r;
}
// D = A*B + C ; A = activations (rows = batch-dup), B = weights (cols = gate rows)
__device__ __forceinline__ f4v mfma_(s8v a, s8v b, f4v c) {
    return __builtin_amdgcn_mfma_f32_16x16x32_bf16(
        __builtin_bit_cast(bf8v, a), __builtin_bit_cast(bf8v, b), c, 0, 0, 0);
}
__device__ __forceinline__ float sig_(float x) {
    return __builtin_amdgcn_rcpf(1.0f + __expf(-x));
}
__device__ __forceinline__ float tanh_(float x) {
    return 1.0f - 2.0f * __builtin_amdgcn_rcpf(1.0f + __expf(2.0f * x));
}
// LDS-flush + raw barrier: does NOT drain vmcnt (x loads stay in flight)
__device__ __forceinline__ void bar_lds() {
    asm volatile("s_waitcnt lgkmcnt(0)" ::: "memory");
    __builtin_amdgcn_s_barrier();
}
// Load an 8-wide B-fragment slice of a weight row, bf16-hi only.
__device__ __forceinline__ s8v load_hi(const float* __restrict__ Wrow, int koff) {
    s8v hi;
    #pragma unroll
    for (int i = 0; i < 8; ++i) hi[i] = (short)f2bf(Wrow[koff + i]);
    return hi;
}
// Build a bf16 A-fragment from 8 in-register floats.
__device__ __forceinline__ s8v xfrag(const float4& a, const float4& b) {
    s8v r; unsigned* ru = (unsigned*)&r;
    ru[0] = cvtpk(a.x, a.y); ru[1] = cvtpk(a.z, a.w);
    ru[2] = cvtpk(b.x, b.y); ru[3] = cvtpk(b.z, b.w);
    return r;
}

__global__ __launch_bounds__(NT, 4)
void lstm_v12(const float* __restrict__ x,     // [B,T,F]
              const float* __restrict__ Wih0,  // [4H,F]
              const float* __restrict__ Whh0,  // [4H,H]
              const float* __restrict__ bih0,
              const float* __restrict__ bhh0,
              const float* __restrict__ Wih1,  // [4H,H]
              const float* __restrict__ Whh1,  // [4H,H]
              const float* __restrict__ bih1,
              const float* __restrict__ bhh1,
              const float* __restrict__ fcw,   // [1,H]
              const float* __restrict__ fcb,   // [1]
              float* __restrict__ out,         // [B]
              int T, int B)
{
    const int tid  = threadIdx.x;
    const int w    = tid >> 6;          // 0..15
    const bool isL0 = (w < 8);
    const int wu   = isL0 ? w : (w - 8);   // unit-octet index 0..7
    const int lane = tid & 63;
    const int j    = lane & 15;         // MFMA col
    const int hi4  = lane >> 4;         // k-slice for frags; batch for pointwise
    const int bm   = j >> 2;            // A-fragment batch row map pi(m)=m>>2
    const int q    = j & 7;             // unit within octet
    const int half = j >> 3;            // 0: gate {i,g} col, 1: gate {f,o} col
    const int u    = 8 * wu + q;        // this col's hidden unit
    const int RA   = 64 * half + u;         // tileA weight row (gate i or f)
    const int RB   = 64 * (2 + half) + u;   // tileB weight row (gate g or o)
    const int b0   = blockIdx.x * NB;

    __shared__ alignas(16) unsigned short h0[2][NB][HS];   // bf16 acts
    __shared__ alignas(16) unsigned short h1[2][NB][HS];
    __shared__ float part[8][4][8];

    for (int i = tid; i < 2 * NB * HS; i += NT) {
        (&h0[0][0][0])[i] = 0;
        (&h1[0][0][0])[i] = 0;
    }

    float c = 0.f;

    if (isL0) {
        // ========== L0 waves: h0(s) from x(s) and h0(s-1) ==========
        s8v wxA, wxB, whA0, whA1, whB0, whB1;
        wxA  = load_hi(&Wih0[RA * F], 8 * hi4);
        wxB  = load_hi(&Wih0[RB * F], 8 * hi4);
        whA0 = load_hi(&Whh0[RA * H], 8 * hi4);
        whA1 = load_hi(&Whh0[RA * H], 32 + 8 * hi4);
        whB0 = load_hi(&Whh0[RB * H], 8 * hi4);
        whB1 = load_hi(&Whh0[RB * H], 32 + 8 * hi4);
        const float biasA = bih0[RA] + bhh0[RA];
        const float biasB = bih0[RB] + bhh0[RB];

        // x direct-load: this lane's 8-float slice of its batch row
        const float* xrow = x + ((size_t)(b0 + bm) * T) * F + 8 * hi4;
        const int tmax = T - 1;
        float4 xA0 = *(const float4*)(xrow);
        float4 xA1 = *(const float4*)(xrow + 4);
        float4 xB0 = *(const float4*)(xrow + F);
        float4 xB1 = *(const float4*)(xrow + F + 4);

        __syncthreads();   // prolog barrier (h zeros visible)

        auto stepL0 = [&](int s, int par, float4& r0, float4& r1) {
            const s8v xf = xfrag(r0, r1);
            const size_t tld = (size_t)((s + 2 < tmax) ? (s + 2) : tmax) * F;
            r0 = *(const float4*)(xrow + tld);
            r1 = *(const float4*)(xrow + tld + 4);

            const s8v hf0 = *(const s8v*)&h0[par ^ 1][bm][8 * hi4];
            const s8v hf1 = *(const s8v*)&h0[par ^ 1][bm][8 * (4 + hi4)];

            __builtin_amdgcn_s_setprio(1);
            f4v aA = {biasA, biasA, biasA, biasA};
            aA = mfma_(xf, wxA, aA);
            f4v bA = {0.f, 0.f, 0.f, 0.f};
            bA = mfma_(hf0, whA0, bA);
            bA = mfma_(hf1, whA1, bA);
            f4v aB = {biasB, biasB, biasB, biasB};
            aB = mfma_(xf, wxB, aB);
            f4v bB = {0.f, 0.f, 0.f, 0.f};
            bB = mfma_(hf0, whB0, bB);
            bB = mfma_(hf1, whB1, bB);
            __builtin_amdgcn_s_setprio(0);

            const float vA = aA[0] + bA[0];   // i (half=0) / f (half=1)
            const float vB = aB[0] + bB[0];   // g (half=0) / o (half=1)
            const float pA = __shfl_xor(vA, 8);
            const float pB = __shfl_xor(vB, 8);
            const float iv = half ? pA : vA;
            const float fv = half ? vA : pA;
            const float gv = half ? pB : vB;
            const float ov = half ? vB : pB;
            const float gi = sig_(iv);
            const float gf = sig_(fv);
            const float gg = tanh_(gv);
            const float go = sig_(ov);
            c = gf * c + gi * gg;
            const float hv = go * tanh_(c);
            if (half == 0) h0[par][hi4][u] = (unsigned short)cvtpk(hv, hv);
            bar_lds();
        };

        #pragma unroll 1
        for (int s = 0; s < T; s += 2) {       // T even
            stepL0(s,     0, xA0, xA1);
            stepL0(s + 1, 1, xB0, xB1);
        }
        bar_lds();   // tail iter s=T: L0 idle (barrier count match)
    } else {
        // ========== L1 waves (lag 1): h1(t=s-1) from h0(t) and h1(t-1) ==========
        s8v wgA0, wgA1, wgB0, wgB1, whA0, whA1, whB0, whB1;
        wgA0 = load_hi(&Wih1[RA * H], 8 * hi4);
        wgA1 = load_hi(&Wih1[RA * H], 32 + 8 * hi4);
        wgB0 = load_hi(&Wih1[RB * H], 8 * hi4);
        wgB1 = load_hi(&Wih1[RB * H], 32 + 8 * hi4);
        whA0 = load_hi(&Whh1[RA * H], 8 * hi4);
        whA1 = load_hi(&Whh1[RA * H], 32 + 8 * hi4);
        whB0 = load_hi(&Whh1[RB * H], 8 * hi4);
        whB1 = load_hi(&Whh1[RB * H], 32 + 8 * hi4);
        const float biasA = bih1[RA] + bhh1[RA];
        const float biasB = bih1[RB] + bhh1[RB];
        const float fcwr  = fcw[u];

        __syncthreads();   // prolog barrier

        auto stepL1 = [&](int s, int par) {
            if (s >= 1) {
                // t = s-1: h0(t) in buf par^1; h1(t-1) in buf par
                const s8v gf0 = *(const s8v*)&h0[par ^ 1][bm][8 * hi4];
                const s8v gf1 = *(const s8v*)&h0[par ^ 1][bm][8 * (4 + hi4)];
                const s8v hf0 = *(const s8v*)&h1[par][bm][8 * hi4];
                const s8v hf1 = *(const s8v*)&h1[par][bm][8 * (4 + hi4)];

                __builtin_amdgcn_s_setprio(1);
                f4v aA = {biasA, biasA, biasA, biasA};
                aA = mfma_(gf0, wgA0, aA);
                aA = mfma_(gf1, wgA1, aA);
                f4v bA = {0.f, 0.f, 0.f, 0.f};
                bA = mfma_(hf0, whA0, bA);
                bA = mfma_(hf1, whA1, bA);
                f4v aB = {biasB, biasB, biasB, biasB};
                aB = mfma_(gf0, wgB0, aB);
                aB = mfma_(gf1, wgB1, aB);
                f4v bB = {0.f, 0.f, 0.f, 0.f};
                bB = mfma_(hf0, whB0, bB);
                bB = mfma_(hf1, whB1, bB);
                __builtin_amdgcn_s_setprio(0);

                const float vA = aA[0] + bA[0];
                const float vB = aB[0] + bB[0];
                const float pA = __shfl_xor(vA, 8);
                const float pB = __shfl_xor(vB, 8);
                const float iv = half ? pA : vA;
                const float fv = half ? vA : pA;
                const float gv = half ? pB : vB;
                const float ov = half ? vB : pB;
                const float gi = sig_(iv);
                const float gf = sig_(fv);
                const float gg = tanh_(gv);
                const float go = sig_(ov);
                c = gf * c + gi * gg;
                const float hv = go * tanh_(c);
                if (s < T) {
                    if (half == 0) h1[par ^ 1][hi4][u] = (unsigned short)cvtpk(hv, hv);
                } else {
                    if (half == 0) part[wu][hi4][q] = hv * fcwr;   // t = T-1
                }
            }
            bar_lds();
        };

        #pragma unroll 1
        for (int s = 0; s < T; s += 2) {       // T even
            stepL1(s,     0);
            stepL1(s + 1, 1);
        }
        stepL1(T, 0);   // tail: computes t=T-1 -> part
    }

    __syncthreads();   // part[] visible

    // ---- fc head: out[b] = sum_u h1(T-1)[b][u]*fcw[u] + fcb ----
    if (tid < 64) {
        const int b = tid >> 4, r = tid & 15;
        float v = 0.f;
        if (r < 8) {
            #pragma unroll
            for (int ww = 0; ww < 8; ++ww) v += part[ww][b][r];
        }
        v += __shfl_xor(v, 1);
        v += __shfl_xor(v, 2);
        v += __shfl_xor(v, 4);
        v += __shfl_xor(v, 8);
        if (r == 0) out[b0 + b] = v + fcb[0];
    }
}

extern "C" void kernel_launch(void* const* d_in, const int* in_sizes, int n_in,
                              void* d_out, int out_size, void* d_ws, size_t ws_size,
                              hipStream_t stream) {
    const float* x    = (const float*)d_in[0];
    const float* Wih0 = (const float*)d_in[1];
    const float* Whh0 = (const float*)d_in[2];
    const float* bih0 = (const float*)d_in[3];
    const float* bhh0 = (const float*)d_in[4];
    const float* Wih1 = (const float*)d_in[5];
    const float* Whh1 = (const float*)d_in[6];
    const float* bih1 = (const float*)d_in[7];
    const float* bhh1 = (const float*)d_in[8];
    const float* fcw  = (const float*)d_in[9];
    const float* fcb  = (const float*)d_in[10];
    float* out = (float*)d_out;

    const int B = out_size;                 // 1024
    const int T = in_sizes[0] / (B * F);    // 512

    dim3 grid(B / NB), block(NT);
    hipLaunchKernelGGL(lstm_v12, grid, block, 0, stream,
                       x, Wih0, Whh0, bih0, bhh0,
                       Wih1, Whh1, bih1, bhh1, fcw, fcb,
                       out, T, B);
}

// Round 13
// 248.805 us; speedup vs baseline: 1.1659x; 1.1659x over previous
//
#include <hip/hip_runtime.h>
#include <math.h>

#define H  64
#define F  32
#define NB 4      // batch columns per block
#define NT 512    // 8 waves: 0-3 = layer0, 4-7 = layer1 (wave-specialized)
#define HS 80     // h row stride (shorts): 160B -> 2-way banks max (free)

typedef __attribute__((ext_vector_type(8))) short   s8v;   // 8 bf16 payload
typedef __attribute__((ext_vector_type(8))) __bf16  bf8v;  // MFMA operand type
typedef __attribute__((ext_vector_type(4))) float   f4v;   // MFMA accumulator

__device__ __forceinline__ unsigned short f2bf(float x) {   // weight init only
    unsigned u = __builtin_bit_cast(unsigned, x);
    u += 0x7FFFu + ((u >> 16) & 1u);          // RNE
    return (unsigned short)(u >> 16);
}
// HW packed f32->bf16 RNE convert (1 instr)
__device__ __forceinline__ unsigned cvtpk(float a, float b) {
    unsigned r;
    asm("v_cvt_pk_bf16_f32 %0, %1, %2" : "=v"(r) : "v"(a), "v"(b));
    return r;
}
// D = A*B + C ; A = activations (rows = batch-dup), B = weights (cols = gate rows)
__device__ __forceinline__ f4v mfma_(s8v a, s8v b, f4v c) {
    return __builtin_amdgcn_mfma_f32_16x16x32_bf16(
        __builtin_bit_cast(bf8v, a), __builtin_bit_cast(bf8v, b), c, 0, 0, 0);
}
__device__ __forceinline__ float sig_(float x) {
    return __builtin_amdgcn_rcpf(1.0f + __expf(-x));
}
__device__ __forceinline__ float tanh_(float x) {
    return 1.0f - 2.0f * __builtin_amdgcn_rcpf(1.0f + __expf(2.0f * x));
}
// LDS-flush + raw barrier: does NOT drain vmcnt (x loads stay in flight)
__device__ __forceinline__ void bar_lds() {
    asm volatile("s_waitcnt lgkmcnt(0)" ::: "memory");
    __builtin_amdgcn_s_barrier();
}
// Load an 8-wide B-fragment slice of a weight row, bf16-hi only.
__device__ __forceinline__ s8v load_hi(const float* __restrict__ Wrow, int koff) {
    s8v hi;
    #pragma unroll
    for (int i = 0; i < 8; ++i) hi[i] = (short)f2bf(Wrow[koff + i]);
    return hi;
}
// Build a bf16 A-fragment from 8 in-register floats.
__device__ __forceinline__ s8v xfrag(const float4& a, const float4& b) {
    s8v r; unsigned* ru = (unsigned*)&r;
    ru[0] = cvtpk(a.x, a.y); ru[1] = cvtpk(a.z, a.w);
    ru[2] = cvtpk(b.x, b.y); ru[3] = cvtpk(b.z, b.w);
    return r;
}

__global__ __launch_bounds__(NT, 2)
void lstm_v13(const float* __restrict__ x,     // [B,T,F]
              const float* __restrict__ Wih0,  // [4H,F]
              const float* __restrict__ Whh0,  // [4H,H]
              const float* __restrict__ bih0,
              const float* __restrict__ bhh0,
              const float* __restrict__ Wih1,  // [4H,H]
              const float* __restrict__ Whh1,  // [4H,H]
              const float* __restrict__ bih1,
              const float* __restrict__ bhh1,
              const float* __restrict__ fcw,   // [1,H]
              const float* __restrict__ fcb,   // [1]
              float* __restrict__ out,         // [B]
              int T, int B)
{
    const int tid  = threadIdx.x;
    const int w    = tid >> 6;          // 0..7
    const int wl   = w & 3;             // wave within its layer group
    const bool isL0 = (w < 4);
    const int lane = tid & 63;
    const int j    = lane & 15;         // MFMA col: unit within wave's 16-unit group
    const int hi4  = lane >> 4;         // k-slice for fragments; batch for pointwise
    const int bm   = j >> 2;            // A-fragment batch row map  pi(m) = m>>2
    const int u    = 16 * wl + j;       // this lane's hidden unit
    const int b0   = blockIdx.x * NB;

    __shared__ alignas(16) unsigned short h0[2][NB][HS];   // bf16 acts
    __shared__ alignas(16) unsigned short h1[2][NB][HS];
    __shared__ float part[4][64];

    for (int i = tid; i < 2 * NB * HS; i += NT) {
        (&h0[0][0][0])[i] = 0;
        (&h1[0][0][0])[i] = 0;
    }

    if (isL0) {
        // ================= LAYER-0 WAVES =================
        // step s: phase A = MFMA(h0(s-1), x(s)); phase B = pointwise -> h0(s), x-prep
        s8v wxh[4];          // Wih0 hi
        s8v whh[4][2];       // Whh0 hi
        float bias[4];
        #pragma unroll
        for (int g = 0; g < 4; ++g) {
            const int R = 64 * g + 16 * wl + j;
            wxh[g] = load_hi(&Wih0[R * F], 8 * hi4);
            whh[g][0] = load_hi(&Whh0[R * H], 8 * hi4);
            whh[g][1] = load_hi(&Whh0[R * H], 32 + 8 * hi4);
            bias[g] = bih0[R] + bhh0[R];
        }
        // x pipeline: xf holds x(s); parity regs hold upcoming rows (distance ~2.5 steps)
        const float* xrow = x + ((size_t)(b0 + bm) * T) * F + 8 * hi4;
        const int tmax = T - 1;
        float4 p0 = *(const float4*)(xrow);
        float4 p1 = *(const float4*)(xrow + 4);
        s8v xf = xfrag(p0, p1);                               // x(0)
        const size_t o1 = (size_t)((1 < tmax) ? 1 : tmax) * F;
        const size_t o2 = (size_t)((2 < tmax) ? 2 : tmax) * F;
        float4 xB0 = *(const float4*)(xrow + o1), xB1 = *(const float4*)(xrow + o1 + 4); // x(1)
        float4 xA0 = *(const float4*)(xrow + o2), xA1 = *(const float4*)(xrow + o2 + 4); // x(2)

        __syncthreads();   // prolog barrier (h zeros visible)

        float c = 0.f;
        f4v accA[4], accB[4];

        auto phA = [&](int s, int par) {
            if (s < T) {
                const s8v hf0 = *(const s8v*)&h0[par ^ 1][bm][8 * hi4];
                const s8v hf1 = *(const s8v*)&h0[par ^ 1][bm][8 * (4 + hi4)];
                __builtin_amdgcn_s_setprio(1);
                #pragma unroll
                for (int g = 0; g < 4; ++g) {
                    f4v av = {bias[g], bias[g], bias[g], bias[g]};
                    accA[g] = mfma_(xf, wxh[g], av);
                    f4v bv = {0.f, 0.f, 0.f, 0.f};
                    bv = mfma_(hf0, whh[g][0], bv);
                    accB[g] = mfma_(hf1, whh[g][1], bv);
                }
                __builtin_amdgcn_s_setprio(0);
            }
            bar_lds();
        };
        auto phB = [&](int s, int par, float4& n0, float4& n1) {
            if (s < T) {
                const float gi = sig_(accA[0][0] + accB[0][0]);
                const float gf = sig_(accA[1][0] + accB[1][0]);
                const float gg = tanh_(accA[2][0] + accB[2][0]);
                const float go = sig_(accA[3][0] + accB[3][0]);
                c = gf * c + gi * gg;
                const float hv = go * tanh_(c);
                h0[par][hi4][u] = (unsigned short)cvtpk(hv, hv);
                // build x(s+1) fragment; refill regs with x(s+3)
                xf = xfrag(n0, n1);
                const size_t tld = (size_t)((s + 3 < tmax) ? (s + 3) : tmax) * F;
                n0 = *(const float4*)(xrow + tld);
                n1 = *(const float4*)(xrow + tld + 4);
            }
            bar_lds();
        };

        #pragma unroll 1
        for (int s = 0; s < T + 2; s += 2) {   // T even
            phA(s, 0);     phB(s, 0, xB0, xB1);
            phA(s + 1, 1); phB(s + 1, 1, xA0, xA1);
        }
    } else {
        // ================= LAYER-1 WAVES =================
        // step s: phase A = pointwise(t=s-2) -> h1(s-2), prefetch h0(s-1);
        //         phase B = MFMA(t=s-1) from h0(s-1), h1(s-2)
        s8v wgh[4][2];       // Wih1 hi
        s8v whh[4][2];       // Whh1 hi
        float bias[4];
        #pragma unroll
        for (int g = 0; g < 4; ++g) {
            const int R = 64 * g + 16 * wl + j;
            wgh[g][0] = load_hi(&Wih1[R * H], 8 * hi4);
            wgh[g][1] = load_hi(&Wih1[R * H], 32 + 8 * hi4);
            whh[g][0] = load_hi(&Whh1[R * H], 8 * hi4);
            whh[g][1] = load_hi(&Whh1[R * H], 32 + 8 * hi4);
            bias[g] = bih1[R] + bhh1[R];
        }
        const float fcwr = fcw[u];
        __syncthreads();   // prolog barrier

        float c = 0.f;
        f4v accA[4], accB[4];

        #pragma unroll 1
        for (int s = 0; s <= T + 1; ++s) {
            const int par = s & 1;
            s8v gf0 = {}, gf1 = {};
            // ---- phase A ----
            if (s >= 1 && s <= T) {
                // prefetch h0(s-1) (stable since bar2 of step s-1); lands during phase A
                gf0 = *(const s8v*)&h0[par ^ 1][bm][8 * hi4];
                gf1 = *(const s8v*)&h0[par ^ 1][bm][8 * (4 + hi4)];
            }
            if (s >= 2) {
                // pointwise for t = s-2 from last step's accumulators
                const float gi = sig_(accA[0][0] + accB[0][0]);
                const float gf = sig_(accA[1][0] + accB[1][0]);
                const float gg = tanh_(accA[2][0] + accB[2][0]);
                const float go = sig_(accA[3][0] + accB[3][0]);
                c = gf * c + gi * gg;
                const float hv = go * tanh_(c);
                if (s <= T) {
                    h1[par][hi4][u] = (unsigned short)cvtpk(hv, hv);   // h1(s-2), parity par
                } else {
                    part[wl][lane] = hv * fcwr;   // t = T-1: fc-head partial
                }
            }
            bar_lds();
            // ---- phase B ----
            if (s >= 1 && s <= T) {
                // h1(s-2) just written (phase A, all L1 waves), parity par
                const s8v hf0 = *(const s8v*)&h1[par][bm][8 * hi4];
                const s8v hf1 = *(const s8v*)&h1[par][bm][8 * (4 + hi4)];
                __builtin_amdgcn_s_setprio(1);
                #pragma unroll
                for (int g = 0; g < 4; ++g) {
                    f4v av = {bias[g], bias[g], bias[g], bias[g]};
                    av = mfma_(gf0, wgh[g][0], av);
                    accA[g] = mfma_(gf1, wgh[g][1], av);
                    f4v bv = {0.f, 0.f, 0.f, 0.f};
                    bv = mfma_(hf0, whh[g][0], bv);
                    accB[g] = mfma_(hf1, whh[g][1], bv);
                }
                __builtin_amdgcn_s_setprio(0);
            }
            bar_lds();
        }
    }

    __syncthreads();   // part[] visible

    // ---- fc head: out[b] = sum_u h1(T-1)[b][u]*fcw[u] + fcb ----
    if (tid < 64) {
        float v = part[0][lane] + part[1][lane] + part[2][lane] + part[3][lane];
        v += __shfl_xor(v, 1);
        v += __shfl_xor(v, 2);
        v += __shfl_xor(v, 4);
        v += __shfl_xor(v, 8);
        if (j == 0) out[b0 + hi4] = v + fcb[0];
    }
}

extern "C" void kernel_launch(void* const* d_in, const int* in_sizes, int n_in,
                              void* d_out, int out_size, void* d_ws, size_t ws_size,
                              hipStream_t stream) {
    const float* x    = (const float*)d_in[0];
    const float* Wih0 = (const float*)d_in[1];
    const float* Whh0 = (const float*)d_in[2];
    const float* bih0 = (const float*)d_in[3];
    const float* bhh0 = (const float*)d_in[4];
    const float* Wih1 = (const float*)d_in[5];
    const float* Whh1 = (const float*)d_in[6];
    const float* bih1 = (const float*)d_in[7];
    const float* bhh1 = (const float*)d_in[8];
    const float* fcw  = (const float*)d_in[9];
    const float* fcb  = (const float*)d_in[10];
    float* out = (float*)d_out;

    const int B = out_size;                 // 1024
    const int T = in_sizes[0] / (B * F);    // 512

    dim3 grid(B / NB), block(NT);
    hipLaunchKernelGGL(lstm_v13, grid, block, 0, stream,
                       x, Wih0, Whh0, bih0, bhh0,
                       Wih1, Whh1, bih1, bhh1, fcw, fcb,
                       out, T, B);
}